// Round 1
// baseline (538.805 us; speedup 1.0000x reference)
//
#include <hip/hip_runtime.h>
#include <hip/hip_bf16.h>
#include <math.h>

#define Bn 32
#define CL 1024
#define QL 128
#define Hh 512
#define NEGV (-1e30f)

typedef short bf16x8 __attribute__((ext_vector_type(8)));
typedef float f32x4 __attribute__((ext_vector_type(4)));

__device__ inline unsigned short f2bf(float x) {
  union { float f; unsigned u; } v; v.f = x;
  unsigned r = v.u + 0x7fff + ((v.u >> 16) & 1);
  return (unsigned short)(r >> 16);
}
__device__ inline unsigned packbf(float x, float y) {
  return (unsigned)f2bf(x) | ((unsigned)f2bf(y) << 16);
}

// ---------------- rowdot: out[r] = dot(X[r,:], w) + bias (cq only now) ----------------
__global__ __launch_bounds__(256) void rowdot_kernel(
    const float* __restrict__ X, const float* __restrict__ w,
    const float* __restrict__ bias, float* __restrict__ out, int nrows) {
  int row = blockIdx.x * 4 + (threadIdx.x >> 6);
  int lane = threadIdx.x & 63;
  if (row >= nrows) return;
  const float* x = X + (size_t)row * Hh;
  float s = 0.f;
  for (int h = lane; h < Hh; h += 64) s += x[h] * w[h];
  for (int off = 32; off > 0; off >>= 1) s += __shfl_down(s, off, 64);
  if (lane == 0) out[row] = s + (bias ? bias[0] : 0.f);
}

// ---------------- prep_q: Qs = bf16(Q*w3), QT = bf16(Q^T) ----------------
__global__ __launch_bounds__(256) void prep_q_kernel(
    const float* __restrict__ Q, const float* __restrict__ w3,
    unsigned short* __restrict__ Qs, unsigned short* __restrict__ QT) {
  __shared__ float tile[QL * 65];  // [j][64 h]
  int b = blockIdx.y, h0 = blockIdx.x * 64, t = threadIdx.x;
  const float* Qb = Q + (size_t)b * QL * Hh;
  unsigned* Qsu = (unsigned*)Qs + (size_t)b * QL * (Hh / 2);
  unsigned* QTu = (unsigned*)QT + ((size_t)b * Hh + h0) * (QL / 2);
  for (int l = 0; l < 16; ++l) {
    int idx = t + l * 256; int c = idx & 31, j = idx >> 5;  // 32 float2 per row
    float2 v = *(const float2*)(Qb + (size_t)j * Hh + h0 + 2 * c);
    float wa = w3[h0 + 2 * c], wb = w3[h0 + 2 * c + 1];
    Qsu[(size_t)j * (Hh / 2) + h0 / 2 + c] = packbf(v.x * wa, v.y * wb);
    tile[j * 65 + 2 * c] = v.x;
    tile[j * 65 + 2 * c + 1] = v.y;
  }
  __syncthreads();
  for (int l = 0; l < 16; ++l) {
    int idx = t + l * 256; int jc = idx & 63, h = idx >> 6;  // 64 j-pairs x 64 h
    QTu[(size_t)h * (QL / 2) + jc] =
        packbf(tile[(2 * jc) * 65 + h], tile[(2 * jc + 1) * 65 + h]);
  }
}

// ---- S = C@(Q*w3)^T + rc + cq; fused: rc, C->bf16 writeback, row softmax, col partials ----
__global__ __launch_bounds__(256) void s_mfma_kernel(
    const float* __restrict__ C, const unsigned short* __restrict__ Qs,
    const float* __restrict__ w1, const int* __restrict__ Qmask,
    const int* __restrict__ Cmask, const float* __restrict__ cq,
    float* __restrict__ S, unsigned short* __restrict__ Prow,
    unsigned short* __restrict__ C16,
    float* __restrict__ partm, float* __restrict__ partl) {
  __shared__ unsigned sA[64 * 32];   // 64 i x 64 k bf16 (swizzled)
  __shared__ unsigned sB[128 * 32];  // 128 j x 64 k bf16 (swizzled)
  __shared__ float rcs[64];
  __shared__ int qm[QL];
  __shared__ int cmk[64];
  __shared__ float swm[4 * QL], swl[4 * QL];
  int b = blockIdx.y, i0 = blockIdx.x * 64, t = threadIdx.x;
  if (t < QL) qm[t] = Qmask[b * QL + t];
  if (t >= 128 && t < 192) cmk[t - 128] = Cmask[b * CL + i0 + (t - 128)];
  __syncthreads();
  int lane = t & 63, w = t >> 6;
  int lanen = lane & 15, quad = lane >> 4;
  int rbase = t >> 5, cc = t & 31;
  f32x4 acc[8];
  for (int nt = 0; nt < 8; ++nt) acc[nt] = (f32x4){0.f, 0.f, 0.f, 0.f};
  float racc[8];
  for (int l = 0; l < 8; ++l) racc[l] = 0.f;
  const float* Cb = C + ((size_t)b * CL + i0) * Hh;
  unsigned* C16u = (unsigned*)C16 + ((size_t)b * CL + i0) * (Hh / 2);
  const unsigned* Qsu = (const unsigned*)Qs + (size_t)b * QL * (Hh / 2);
  for (int k0 = 0; k0 < Hh; k0 += 64) {
    float2 wv = *(const float2*)(w1 + k0 + 2 * cc);
    for (int l = 0; l < 8; ++l) {  // A: 64x64 fp32 -> bf16 + writeback + rc partial
      int rr = rbase + l * 8;
      float2 v = *(const float2*)(Cb + (size_t)rr * Hh + k0 + 2 * cc);
      unsigned pk = packbf(v.x, v.y);
      sA[rr * 32 + (cc ^ ((rr & 7) << 2))] = pk;
      C16u[(size_t)rr * (Hh / 2) + k0 / 2 + cc] = pk;
      racc[l] += v.x * wv.x + v.y * wv.y;
    }
    for (int l = 0; l < 16; ++l) {  // B: 128x64 bf16 copy
      int idx = t + l * 256; int c = idx & 31, j = idx >> 5;
      sB[j * 32 + (c ^ ((j & 7) << 2))] = Qsu[(size_t)j * (Hh / 2) + k0 / 2 + c];
    }
    __syncthreads();
    for (int kk = 0; kk < 2; ++kk) {
      int arow = w * 16 + lanen;
      bf16x8 a = *(const bf16x8*)(sA + arow * 32 + ((kk * 16 + quad * 4) ^ ((arow & 7) << 2)));
      for (int nt = 0; nt < 8; ++nt) {
        int brow = nt * 16 + lanen;
        bf16x8 bb = *(const bf16x8*)(sB + brow * 32 + ((kk * 16 + quad * 4) ^ ((brow & 7) << 2)));
        acc[nt] = __builtin_amdgcn_mfma_f32_16x16x32_bf16(a, bb, acc[nt], 0, 0, 0);
      }
    }
    __syncthreads();
  }
  // rc reduction over the 32 lanes sharing each row
  for (int l = 0; l < 8; ++l) {
    float s = racc[l];
    for (int off = 1; off <= 16; off <<= 1) s += __shfl_xor(s, off, 64);
    if (cc == 0) rcs[rbase + l * 8] = s;
  }
  __syncthreads();
  float cqv[8]; int qmv[8];
  for (int nt = 0; nt < 8; ++nt) {
    int j = nt * 16 + lanen;
    cqv[nt] = cq[b * QL + j];
    qmv[nt] = qm[j];
  }
  float colM[8], colL[8];
  for (int nt = 0; nt < 8; ++nt) { colM[nt] = -INFINITY; colL[nt] = 0.f; }
  int rowbase = i0 + w * 16 + quad * 4;
  for (int r = 0; r < 4; ++r) {
    int row = rowbase + r;
    float rcv = rcs[w * 16 + quad * 4 + r];
    int cmr = cmk[w * 16 + quad * 4 + r];
    float vals[8], mv = -INFINITY;
    for (int nt = 0; nt < 8; ++nt) {
      float val = acc[nt][r] + rcv + cqv[nt];
      vals[nt] = val;
      mv = fmaxf(mv, qmv[nt] ? val : NEGV);
    }
    for (int off = 1; off < 16; off <<= 1) mv = fmaxf(mv, __shfl_xor(mv, off, 64));
    float ls = 0.f;
    for (int nt = 0; nt < 8; ++nt) ls += __expf((qmv[nt] ? vals[nt] : NEGV) - mv);
    for (int off = 1; off < 16; off <<= 1) ls += __shfl_xor(ls, off, 64);
    float linv = 1.f / ls;
    size_t base = ((size_t)b * CL + row) * QL;
    for (int nt = 0; nt < 8; ++nt) {
      int j = nt * 16 + lanen;
      S[base + j] = vals[nt];
      Prow[base + j] = f2bf(__expf((qmv[nt] ? vals[nt] : NEGV) - mv) * linv);
      float v = cmr ? vals[nt] : NEGV;
      float nm = fmaxf(colM[nt], v);
      colL[nt] = colL[nt] * __expf(colM[nt] - nm) + __expf(v - nm);
      colM[nt] = nm;
    }
  }
  // reduce column partials across the 4 quads (rows of this wave)
  for (int off = 16; off <= 32; off <<= 1) {
    for (int nt = 0; nt < 8; ++nt) {
      float m2 = __shfl_xor(colM[nt], off, 64);
      float l2 = __shfl_xor(colL[nt], off, 64);
      float nm = fmaxf(colM[nt], m2);
      colL[nt] = colL[nt] * __expf(colM[nt] - nm) + l2 * __expf(m2 - nm);
      colM[nt] = nm;
    }
  }
  if (quad == 0) {
    for (int nt = 0; nt < 8; ++nt) {
      swm[w * QL + nt * 16 + lanen] = colM[nt];
      swl[w * QL + nt * 16 + lanen] = colL[nt];
    }
  }
  __syncthreads();
  if (t < QL) {
    float m = -INFINITY, L = 0.f;
    for (int ww = 0; ww < 4; ++ww) {
      float m2 = swm[ww * QL + t], l2 = swl[ww * QL + t];
      float nm = fmaxf(m, m2);
      L = L * __expf(m - nm) + l2 * __expf(m2 - nm);
      m = nm;
    }
    partm[((size_t)b * 16 + blockIdx.x) * QL + t] = m;
    partl[((size_t)b * 16 + blockIdx.x) * QL + t] = L;
  }
}

// ---------------- column softmax stats, stage 2 ----------------
__global__ __launch_bounds__(128) void colstat2_kernel(
    const float* __restrict__ partm, const float* __restrict__ partl,
    float* __restrict__ colm, float* __restrict__ colinv) {
  int b = blockIdx.x, j = threadIdx.x;
  float m = -INFINITY, L = 0.f;
  for (int c = 0; c < 16; ++c) {
    float m2 = partm[(b * 16 + c) * QL + j], l2 = partl[(b * 16 + c) * QL + j];
    float nm = fmaxf(m, m2);
    L = L * __expf(m - nm) + l2 * __expf(m2 - nm);
    m = nm;
  }
  colm[b * QL + j] = m;
  colinv[b * QL + j] = 1.f / L;
}

// ---------------- P_col^T bf16 [b][j][i] ----------------
__global__ __launch_bounds__(256) void pcol_kernel(
    const float* __restrict__ S, const int* __restrict__ Cmask,
    const float* __restrict__ colm, const float* __restrict__ colinv,
    unsigned short* __restrict__ PT) {
  __shared__ float tile[64 * 129];
  __shared__ int cm[64];
  __shared__ float cmj[QL], civ[QL];
  int b = blockIdx.y, i0 = blockIdx.x * 64, t = threadIdx.x;
  if (t < 64) cm[t] = Cmask[b * CL + i0 + t];
  if (t >= 128) { int j = t - 128; cmj[j] = colm[b * QL + j]; civ[j] = colinv[b * QL + j]; }
  __syncthreads();
  const float* Sb = S + ((size_t)b * CL + i0) * QL;
  for (int l = 0; l < 32; ++l) {
    int idx = t + l * 256; int j = idx & 127, il = idx >> 7;
    float v = cm[il] ? Sb[(size_t)il * QL + j] : NEGV;
    tile[il * 129 + j] = __expf(v - cmj[j]) * civ[j];
  }
  __syncthreads();
  unsigned* PTu = (unsigned*)PT;
  for (int l = 0; l < 16; ++l) {
    int idx = t + l * 256; int c = idx & 31, j = idx >> 5;
    PTu[(((size_t)b * QL + j) * CL + i0) / 2 + c] =
        packbf(tile[(2 * c) * 129 + j], tile[(2 * c + 1) * 129 + j]);
  }
}

// ---------------- TT[h][j] = sum_i C^T[h,i] * Pcol[i,j]  (bf16 in, bf16 out) ----------------
__global__ __launch_bounds__(256) void t_mfma_kernel(
    const unsigned short* __restrict__ C16, const unsigned short* __restrict__ PT,
    unsigned short* __restrict__ TT) {
  __shared__ unsigned ct[64 * 17];   // raw [64 i][32 h] bf16 pairs (u32 along h)
  __shared__ unsigned sA[32 * 32];   // [32 h][64 i] bf16 (swizzled)
  __shared__ unsigned sB[128 * 32];  // [128 j][64 i] bf16 (swizzled)
  int b = blockIdx.y, h0 = blockIdx.x * 32, t = threadIdx.x;
  int lane = t & 63, w = t >> 6;
  int lanen = lane & 15, quad = lane >> 4;
  int mw = w >> 1, nw = w & 1;
  f32x4 acc[4];
  for (int nt = 0; nt < 4; ++nt) acc[nt] = (f32x4){0.f, 0.f, 0.f, 0.f};
  const unsigned* C16u = (const unsigned*)C16 + (size_t)b * CL * (Hh / 2) + h0 / 2;
  const unsigned* PTu = (const unsigned*)PT + (size_t)b * QL * (CL / 2);
  const unsigned short* ct16 = (const unsigned short*)ct;
  for (int i0 = 0; i0 < CL; i0 += 64) {
    for (int l = 0; l < 4; ++l) {  // C16 tile [64 i][16 u32]
      int idx = t + l * 256; int hc = idx & 15, ii = idx >> 4;
      ct[ii * 17 + hc] = C16u[(size_t)(i0 + ii) * (Hh / 2) + hc];
    }
    for (int l = 0; l < 16; ++l) {  // PT tile [128 j][32 u32]
      int idx = t + l * 256; int c = idx & 31, j = idx >> 5;
      sB[j * 32 + (c ^ ((j & 7) << 2))] = PTu[(size_t)j * (CL / 2) + i0 / 2 + c];
    }
    __syncthreads();
    for (int l = 0; l < 4; ++l) {  // transpose-pack: sA[h][i-pair]
      int idx = t + l * 256; int c = idx & 31, hh = idx >> 5;
      unsigned lo = ct16[(2 * c) * 34 + hh];
      unsigned hi = ct16[(2 * c + 1) * 34 + hh];
      sA[hh * 32 + (c ^ ((hh & 7) << 2))] = lo | (hi << 16);
    }
    __syncthreads();
    for (int kk = 0; kk < 2; ++kk) {
      int arow = mw * 16 + lanen;
      bf16x8 a = *(const bf16x8*)(sA + arow * 32 + ((kk * 16 + quad * 4) ^ ((arow & 7) << 2)));
      for (int nt = 0; nt < 4; ++nt) {
        int brow = nw * 64 + nt * 16 + lanen;
        bf16x8 bb = *(const bf16x8*)(sB + brow * 32 + ((kk * 16 + quad * 4) ^ ((brow & 7) << 2)));
        acc[nt] = __builtin_amdgcn_mfma_f32_16x16x32_bf16(a, bb, acc[nt], 0, 0, 0);
      }
    }
    __syncthreads();
  }
  for (int nt = 0; nt < 4; ++nt)
    for (int r = 0; r < 4; ++r) {
      int h = h0 + mw * 16 + quad * 4 + r;
      int j = nw * 64 + nt * 16 + lanen;
      TT[((size_t)b * Hh + h) * QL + j] = f2bf(acc[nt][r]);
    }
}

// ---------------- out: A = P@Q, Bm = P@T; single K=128 phase ----------------
__global__ __launch_bounds__(256) void out_mfma_kernel(
    const unsigned short* __restrict__ Prow, const unsigned short* __restrict__ TT,
    const unsigned short* __restrict__ QT, const float* __restrict__ C,
    float* __restrict__ out) {
  __shared__ unsigned sP[64 * 64];
  __shared__ unsigned sQ[64 * 64];
  __shared__ unsigned sT[64 * 64];
  int b = blockIdx.z, i0 = blockIdx.y * 64, h0 = blockIdx.x * 64, t = threadIdx.x;
  int lane = t & 63, w = t >> 6;
  int lanen = lane & 15, quad = lane >> 4;
  const unsigned* Pu = (const unsigned*)Prow + ((size_t)b * CL + i0) * (QL / 2);
  const unsigned* Tu = (const unsigned*)TT + ((size_t)b * Hh + h0) * (QL / 2);
  const unsigned* Qu = (const unsigned*)QT + ((size_t)b * Hh + h0) * (QL / 2);
  for (int l = 0; l < 16; ++l) {
    int idx = t + l * 256; int c = idx & 63, rr = idx >> 6;
    int cs = c ^ ((rr & 7) << 2);
    sP[rr * 64 + cs] = Pu[(size_t)rr * 64 + c];
    sQ[rr * 64 + cs] = Qu[(size_t)rr * 64 + c];
    sT[rr * 64 + cs] = Tu[(size_t)rr * 64 + c];
  }
  __syncthreads();
  f32x4 accA[4], accB[4];
  for (int nt = 0; nt < 4; ++nt) {
    accA[nt] = (f32x4){0.f, 0.f, 0.f, 0.f};
    accB[nt] = (f32x4){0.f, 0.f, 0.f, 0.f};
  }
  for (int kk = 0; kk < 4; ++kk) {
    int arow = w * 16 + lanen;
    bf16x8 a = *(const bf16x8*)(sP + arow * 64 + ((kk * 16 + quad * 4) ^ ((arow & 7) << 2)));
    for (int nt = 0; nt < 4; ++nt) {
      int brow = nt * 16 + lanen;
      int boff = brow * 64 + ((kk * 16 + quad * 4) ^ ((brow & 7) << 2));
      bf16x8 bq = *(const bf16x8*)(sQ + boff);
      bf16x8 bt = *(const bf16x8*)(sT + boff);
      accA[nt] = __builtin_amdgcn_mfma_f32_16x16x32_bf16(a, bq, accA[nt], 0, 0, 0);
      accB[nt] = __builtin_amdgcn_mfma_f32_16x16x32_bf16(a, bt, accB[nt], 0, 0, 0);
    }
  }
  for (int r = 0; r < 4; ++r) {
    int i = i0 + w * 16 + quad * 4 + r;
    const float* Crow = C + ((size_t)b * CL + i) * Hh;
    float* orow = out + ((size_t)b * CL + i) * (size_t)(4 * Hh);
    for (int nt = 0; nt < 4; ++nt) {
      int h = h0 + nt * 16 + lanen;
      float cv = Crow[h];
      float av = accA[nt][r], bv = accB[nt][r];
      orow[h] = cv;
      orow[Hh + h] = av;
      orow[2 * Hh + h] = cv * av;
      orow[3 * Hh + h] = cv * bv;
    }
  }
}

extern "C" void kernel_launch(void* const* d_in, const int* in_sizes, int n_in,
                              void* d_out, int out_size, void* d_ws, size_t ws_size,
                              hipStream_t stream) {
  const float* C = (const float*)d_in[0];
  const float* Q = (const float*)d_in[1];
  const int* Cmask = (const int*)d_in[2];
  const int* Qmask = (const int*)d_in[3];
  const float* w = (const float*)d_in[4];
  const float* bptr = (const float*)d_in[5];
  float* out = (float*)d_out;
  float* f = (float*)d_ws;

  // workspace layout (floats, then shorts)
  float* cq     = f;                   // 4096
  float* colm   = f + 4096;            // 4096
  float* colinv = f + 8192;            // 4096
  float* partm  = f + 12288;           // 65536
  float* partl  = f + 77824;           // 65536
  float* S      = f + 143360;          // 4194304 (16 MB)
  unsigned short* Prow = (unsigned short*)(f + 4337664);  // 8 MB
  unsigned short* PT   = Prow + 4194304;                  // 8 MB
  unsigned short* TT   = PT + 4194304;                    // 4 MB
  unsigned short* C16  = TT + 2097152;                    // 32 MB
  unsigned short* Qs   = C16 + 16777216;                  // 4 MB
  unsigned short* QT   = Qs + 2097152;                    // 4 MB (total ~80 MB)

  rowdot_kernel<<<dim3((Bn * QL) / 4), 256, 0, stream>>>(Q, w + Hh, bptr, cq, Bn * QL);
  prep_q_kernel<<<dim3(Hh / 64, Bn), 256, 0, stream>>>(Q, w + 2 * Hh, Qs, QT);
  s_mfma_kernel<<<dim3(CL / 64, Bn), 256, 0, stream>>>(C, Qs, w, Qmask, Cmask, cq, S,
                                                       Prow, C16, partm, partl);
  colstat2_kernel<<<dim3(Bn), 128, 0, stream>>>(partm, partl, colm, colinv);
  pcol_kernel<<<dim3(CL / 64, Bn), 256, 0, stream>>>(S, Cmask, colm, colinv, PT);
  t_mfma_kernel<<<dim3(Hh / 32, Bn), 256, 0, stream>>>(C16, PT, TT);
  out_mfma_kernel<<<dim3(Hh / 64, CL / 64, Bn), 256, 0, stream>>>(Prow, TT, QT, C, out);
}

// Round 2
// 481.110 us; speedup vs baseline: 1.1199x; 1.1199x over previous
//
#include <hip/hip_runtime.h>
#include <hip/hip_bf16.h>
#include <math.h>

#define Bn 32
#define CL 1024
#define QL 128
#define Hh 512
#define NEGV (-1e30f)

typedef short bf16x8 __attribute__((ext_vector_type(8)));
typedef float f32x4 __attribute__((ext_vector_type(4)));

__device__ inline unsigned short f2bf(float x) {
  union { float f; unsigned u; } v; v.f = x;
  unsigned r = v.u + 0x7fff + ((v.u >> 16) & 1);
  return (unsigned short)(r >> 16);
}
__device__ inline unsigned packbf(float x, float y) {
  return (unsigned)f2bf(x) | ((unsigned)f2bf(y) << 16);
}

// ---------------- rowdot: out[r] = dot(X[r,:], w) + bias ----------------
__global__ __launch_bounds__(256) void rowdot_kernel(
    const float* __restrict__ X, const float* __restrict__ w,
    const float* __restrict__ bias, float* __restrict__ out, int nrows) {
  int row = blockIdx.x * 4 + (threadIdx.x >> 6);
  int lane = threadIdx.x & 63;
  if (row >= nrows) return;
  const float* x = X + (size_t)row * Hh;
  float s = 0.f;
  for (int h = lane; h < Hh; h += 64) s += x[h] * w[h];
  for (int off = 32; off > 0; off >>= 1) s += __shfl_down(s, off, 64);
  if (lane == 0) out[row] = s + (bias ? bias[0] : 0.f);
}

// ---------------- prep_q: QT = bf16(Q^T) once (for out_mfma) ----------------
__global__ __launch_bounds__(256) void prep_q_kernel(
    const float* __restrict__ Q, unsigned short* __restrict__ QT) {
  __shared__ float tile[QL * 65];  // [j][64 h]
  int b = blockIdx.y, h0 = blockIdx.x * 64, t = threadIdx.x;
  const float* Qb = Q + (size_t)b * QL * Hh;
  unsigned* QTu = (unsigned*)QT + ((size_t)b * Hh + h0) * (QL / 2);
  for (int l = 0; l < 16; ++l) {
    int idx = t + l * 256; int c = idx & 31, j = idx >> 5;  // 32 float2 per row
    float2 v = *(const float2*)(Qb + (size_t)j * Hh + h0 + 2 * c);
    tile[j * 65 + 2 * c] = v.x;
    tile[j * 65 + 2 * c + 1] = v.y;
  }
  __syncthreads();
  for (int l = 0; l < 16; ++l) {
    int idx = t + l * 256; int jc = idx & 63, h = idx >> 6;  // 64 j-pairs x 64 h
    QTu[(size_t)h * (QL / 2) + jc] =
        packbf(tile[(2 * jc) * 65 + h], tile[(2 * jc + 1) * 65 + h]);
  }
}

// ---------------- S = (C*w3)@Q^T + rc + cq; row softmax -> S fp32 + P_row bf16 ----
__global__ __launch_bounds__(256) void s_mfma_kernel(
    const float* __restrict__ C, const float* __restrict__ Q,
    const float* __restrict__ w3, const int* __restrict__ Qmask,
    const float* __restrict__ rc, const float* __restrict__ cq,
    float* __restrict__ S, unsigned short* __restrict__ Prow) {
  __shared__ unsigned sA[64 * 16];   // 64 rows x 32 bf16 (C*w3)
  __shared__ unsigned sB[128 * 16];  // 128 rows x 32 bf16 (Q)
  __shared__ float sW[Hh];
  __shared__ int qm[QL];
  int b = blockIdx.y, i0 = blockIdx.x * 64, t = threadIdx.x;
  if (t < QL) qm[t] = Qmask[b * QL + t];
  for (int l = t; l < Hh; l += 256) sW[l] = w3[l];
  __syncthreads();
  int lane = t & 63, w = t >> 6;
  int lanen = lane & 15, quad = lane >> 4;
  f32x4 acc[8];
  for (int nt = 0; nt < 8; ++nt) acc[nt] = (f32x4){0.f, 0.f, 0.f, 0.f};
  const float* Cb = C + ((size_t)b * CL + i0) * Hh;
  const float* Qb = Q + (size_t)b * QL * Hh;
  for (int k0 = 0; k0 < Hh; k0 += 32) {
    for (int l = 0; l < 4; ++l) {                 // A: 64x32
      int idx = t + l * 256; int c = idx & 15, rr = idx >> 4;
      float2 v = *(const float2*)(Cb + (size_t)rr * Hh + k0 + c * 2);
      sA[rr * 16 + c] = packbf(v.x * sW[k0 + c * 2], v.y * sW[k0 + c * 2 + 1]);
    }
    for (int l = 0; l < 8; ++l) {                 // B: 128x32
      int idx = t + l * 256; int c = idx & 15, j = idx >> 4;
      float2 v = *(const float2*)(Qb + (size_t)j * Hh + k0 + c * 2);
      sB[j * 16 + c] = packbf(v.x, v.y);
    }
    __syncthreads();
    bf16x8 a = *(const bf16x8*)(sA + (w * 16 + lanen) * 16 + quad * 4);
    for (int nt = 0; nt < 8; ++nt) {
      bf16x8 bb = *(const bf16x8*)(sB + (nt * 16 + lanen) * 16 + quad * 4);
      acc[nt] = __builtin_amdgcn_mfma_f32_16x16x32_bf16(a, bb, acc[nt], 0, 0, 0);
    }
    __syncthreads();
  }
  float cqv[8]; int qmv[8];
  for (int nt = 0; nt < 8; ++nt) {
    int j = nt * 16 + lanen;
    cqv[nt] = cq[b * QL + j]; qmv[nt] = qm[j];
  }
  int rowbase = i0 + w * 16 + quad * 4;
  for (int r = 0; r < 4; ++r) {
    int row = rowbase + r;
    float rcv = rc[b * CL + row];
    float vals[8], mv = -INFINITY;
    for (int nt = 0; nt < 8; ++nt) {
      float val = acc[nt][r] + rcv + cqv[nt];
      vals[nt] = val;
      mv = fmaxf(mv, qmv[nt] ? val : NEGV);
    }
    for (int off = 1; off < 16; off <<= 1) mv = fmaxf(mv, __shfl_xor(mv, off, 64));
    float ls = 0.f;
    for (int nt = 0; nt < 8; ++nt) ls += __expf((qmv[nt] ? vals[nt] : NEGV) - mv);
    for (int off = 1; off < 16; off <<= 1) ls += __shfl_xor(ls, off, 64);
    float linv = 1.f / ls;
    size_t base = ((size_t)b * CL + row) * QL;
    for (int nt = 0; nt < 8; ++nt) {
      int j = nt * 16 + lanen;
      S[base + j] = vals[nt];
      Prow[base + j] = f2bf(__expf((qmv[nt] ? vals[nt] : NEGV) - mv) * linv);
    }
  }
}

// ---------------- column softmax stats, 2-stage ----------------
__global__ __launch_bounds__(256) void colstat1_kernel(
    const float* __restrict__ S, const int* __restrict__ Cmask,
    float* __restrict__ partm, float* __restrict__ partl) {
  __shared__ int cm[64];
  __shared__ float sm[QL], sl[QL];
  int b = blockIdx.y, chunk = blockIdx.x, t = threadIdx.x;
  int i0 = chunk * 64;
  if (t < 64) cm[t] = Cmask[b * CL + i0 + t];
  __syncthreads();
  int j = t & 127, ir = t >> 7;
  float m = -INFINITY, l = 0.f;
  const float* Sb = S + ((size_t)b * CL + i0) * QL;
  for (int i = ir; i < 64; i += 2) {
    float v = cm[i] ? Sb[(size_t)i * QL + j] : NEGV;
    float nm = fmaxf(m, v);
    l = l * __expf(m - nm) + __expf(v - nm);
    m = nm;
  }
  if (ir == 1) { sm[j] = m; sl[j] = l; }
  __syncthreads();
  if (ir == 0) {
    float m2 = sm[j], l2 = sl[j];
    float nm = fmaxf(m, m2);
    float L = l * __expf(m - nm) + l2 * __expf(m2 - nm);
    partm[(b * 16 + chunk) * QL + j] = nm;
    partl[(b * 16 + chunk) * QL + j] = L;
  }
}

__global__ __launch_bounds__(128) void colstat2_kernel(
    const float* __restrict__ partm, const float* __restrict__ partl,
    float* __restrict__ colm, float* __restrict__ colinv) {
  int b = blockIdx.x, j = threadIdx.x;
  float m = -INFINITY, L = 0.f;
  for (int c = 0; c < 16; ++c) {
    float m2 = partm[(b * 16 + c) * QL + j], l2 = partl[(b * 16 + c) * QL + j];
    float nm = fmaxf(m, m2);
    L = L * __expf(m - nm) + l2 * __expf(m2 - nm);
    m = nm;
  }
  colm[b * QL + j] = m;
  colinv[b * QL + j] = 1.f / L;
}

// ---------------- P_col^T bf16 [b][j][i] ----------------
__global__ __launch_bounds__(256) void pcol_kernel(
    const float* __restrict__ S, const int* __restrict__ Cmask,
    const float* __restrict__ colm, const float* __restrict__ colinv,
    unsigned short* __restrict__ PT) {
  __shared__ float tile[64 * 129];
  __shared__ int cm[64];
  __shared__ float cmj[QL], civ[QL];
  int b = blockIdx.y, i0 = blockIdx.x * 64, t = threadIdx.x;
  if (t < 64) cm[t] = Cmask[b * CL + i0 + t];
  if (t >= 128) { int j = t - 128; cmj[j] = colm[b * QL + j]; civ[j] = colinv[b * QL + j]; }
  __syncthreads();
  const float* Sb = S + ((size_t)b * CL + i0) * QL;
  for (int l = 0; l < 32; ++l) {
    int idx = t + l * 256; int j = idx & 127, il = idx >> 7;
    float v = cm[il] ? Sb[(size_t)il * QL + j] : NEGV;
    tile[il * 129 + j] = __expf(v - cmj[j]) * civ[j];
  }
  __syncthreads();
  unsigned* PTu = (unsigned*)PT;
  for (int l = 0; l < 16; ++l) {
    int idx = t + l * 256; int c = idx & 31, j = idx >> 5;
    PTu[(((size_t)b * QL + j) * CL + i0) / 2 + c] =
        packbf(tile[(2 * c) * 129 + j], tile[(2 * c + 1) * 129 + j]);
  }
}

// ---------------- TT[h][j] = sum_i C^T[h,i] * Pcol[i,j]  (bf16 out) ----------------
__global__ __launch_bounds__(256) void t_mfma_kernel(
    const float* __restrict__ C, const unsigned short* __restrict__ PT,
    unsigned short* __restrict__ TT) {
  __shared__ float ftile[32 * 33];
  __shared__ unsigned sA[32 * 16];   // 32 h x 32 i bf16
  __shared__ unsigned sB[128 * 16];  // 128 j x 32 i bf16
  int b = blockIdx.y, h0 = blockIdx.x * 32, t = threadIdx.x;
  int lane = t & 63, w = t >> 6;
  int lanen = lane & 15, quad = lane >> 4;
  int mw = w >> 1, nw = w & 1;
  f32x4 acc[4];
  for (int nt = 0; nt < 4; ++nt) acc[nt] = (f32x4){0.f, 0.f, 0.f, 0.f};
  const float* Cb = C + (size_t)b * CL * Hh;
  const unsigned* PTu = (const unsigned*)PT + ((size_t)b * QL * CL) / 2;
  for (int i0 = 0; i0 < CL; i0 += 32) {
    for (int l = 0; l < 4; ++l) {                 // fp32 C tile, coalesced
      int idx = t + l * 256; int hh = idx & 31, ii = idx >> 5;
      ftile[ii * 33 + hh] = Cb[(size_t)(i0 + ii) * Hh + h0 + hh];
    }
    for (int l = 0; l < 8; ++l) {                 // B: PT direct copy
      int idx = t + l * 256; int c = idx & 15, j = idx >> 4;
      sB[j * 16 + c] = PTu[(size_t)j * (CL / 2) + i0 / 2 + c];
    }
    __syncthreads();
    for (int l = 0; l < 2; ++l) {                 // transpose-pack A
      int idx = t + l * 256; int c = idx & 15, hh = idx >> 4;
      sA[hh * 16 + c] = packbf(ftile[(2 * c) * 33 + hh], ftile[(2 * c + 1) * 33 + hh]);
    }
    __syncthreads();
    bf16x8 a = *(const bf16x8*)(sA + (mw * 16 + lanen) * 16 + quad * 4);
    for (int nt = 0; nt < 4; ++nt) {
      bf16x8 bb = *(const bf16x8*)(sB + (nw * 64 + nt * 16 + lanen) * 16 + quad * 4);
      acc[nt] = __builtin_amdgcn_mfma_f32_16x16x32_bf16(a, bb, acc[nt], 0, 0, 0);
    }
    __syncthreads();
  }
  for (int nt = 0; nt < 4; ++nt)
    for (int r = 0; r < 4; ++r) {
      int h = h0 + mw * 16 + quad * 4 + r;
      int j = nw * 64 + nt * 16 + lanen;
      TT[((size_t)b * Hh + h) * QL + j] = f2bf(acc[nt][r]);
    }
}

// ---- out: A = P@Q, Bm = P@T; single K=128 phase, LDS-staged coalesced epilogue ----
__global__ __launch_bounds__(256) void out_mfma_kernel(
    const unsigned short* __restrict__ Prow, const unsigned short* __restrict__ TT,
    const unsigned short* __restrict__ QT, const float* __restrict__ C,
    float* __restrict__ out) {
  __shared__ unsigned smem[3 * 64 * 64];  // 48 KB: staging sP/sQ/sT, reused as epilogue f32
  unsigned* sP = smem;
  unsigned* sQ = smem + 64 * 64;
  unsigned* sT = smem + 2 * 64 * 64;
  int b = blockIdx.z, i0 = blockIdx.y * 64, h0 = blockIdx.x * 64, t = threadIdx.x;
  int lane = t & 63, w = t >> 6;
  int lanen = lane & 15, quad = lane >> 4;
  const unsigned* Pu = (const unsigned*)Prow + ((size_t)b * CL + i0) * (QL / 2);
  const unsigned* Tu = (const unsigned*)TT + ((size_t)b * Hh + h0) * (QL / 2);
  const unsigned* Qu = (const unsigned*)QT + ((size_t)b * Hh + h0) * (QL / 2);
  for (int l = 0; l < 16; ++l) {
    int idx = t + l * 256; int c = idx & 63, rr = idx >> 6;
    int cs = c ^ ((rr & 7) << 2);
    sP[rr * 64 + cs] = Pu[(size_t)rr * 64 + c];
    sQ[rr * 64 + cs] = Qu[(size_t)rr * 64 + c];
    sT[rr * 64 + cs] = Tu[(size_t)rr * 64 + c];
  }
  __syncthreads();
  f32x4 accA[4], accB[4];
  for (int nt = 0; nt < 4; ++nt) {
    accA[nt] = (f32x4){0.f, 0.f, 0.f, 0.f};
    accB[nt] = (f32x4){0.f, 0.f, 0.f, 0.f};
  }
  for (int kk = 0; kk < 4; ++kk) {
    int arow = w * 16 + lanen;
    bf16x8 a = *(const bf16x8*)(sP + arow * 64 + ((kk * 16 + quad * 4) ^ ((arow & 7) << 2)));
    for (int nt = 0; nt < 4; ++nt) {
      int brow = nt * 16 + lanen;
      int boff = brow * 64 + ((kk * 16 + quad * 4) ^ ((brow & 7) << 2));
      bf16x8 bq = *(const bf16x8*)(sQ + boff);
      bf16x8 bt = *(const bf16x8*)(sT + boff);
      accA[nt] = __builtin_amdgcn_mfma_f32_16x16x32_bf16(a, bq, accA[nt], 0, 0, 0);
      accB[nt] = __builtin_amdgcn_mfma_f32_16x16x32_bf16(a, bt, accB[nt], 0, 0, 0);
    }
  }
  __syncthreads();  // all waves done reading sP/sQ/sT before reuse
  float* fA = (float*)smem;             // 64x65 f32
  float* fB = (float*)smem + 64 * 65;   // 64x65 f32 (33.3 KB total, fits in 48 KB)
  for (int nt = 0; nt < 4; ++nt)
    for (int r = 0; r < 4; ++r) {
      int iL = w * 16 + quad * 4 + r;
      int hL = nt * 16 + lanen;
      fA[iL * 65 + hL] = accA[nt][r];
      fB[iL * 65 + hL] = accB[nt][r];
    }
  __syncthreads();
  // wave w writes rows w*16..w*16+15; lane indexes h -> 256B contiguous stores
  for (int rr = 0; rr < 16; ++rr) {
    int iL = w * 16 + rr;
    int i = i0 + iL;
    const float* Crow = C + ((size_t)b * CL + i) * Hh + h0;
    float* orow = out + ((size_t)b * CL + i) * (size_t)(4 * Hh) + h0;
    float cv = Crow[lane];
    float av = fA[iL * 65 + lane];
    float bv = fB[iL * 65 + lane];
    orow[lane] = cv;
    orow[Hh + lane] = av;
    orow[2 * Hh + lane] = cv * av;
    orow[3 * Hh + lane] = cv * bv;
  }
}

extern "C" void kernel_launch(void* const* d_in, const int* in_sizes, int n_in,
                              void* d_out, int out_size, void* d_ws, size_t ws_size,
                              hipStream_t stream) {
  const float* C = (const float*)d_in[0];
  const float* Q = (const float*)d_in[1];
  const int* Cmask = (const int*)d_in[2];
  const int* Qmask = (const int*)d_in[3];
  const float* w = (const float*)d_in[4];
  const float* bptr = (const float*)d_in[5];
  float* out = (float*)d_out;
  float* f = (float*)d_ws;

  // workspace layout
  float* rc     = f;                  // 32768
  float* cq     = f + 32768;          // 4096
  float* colm   = f + 36864;          // 4096
  float* colinv = f + 40960;          // 4096
  float* partm  = f + 45056;          // 65536
  float* partl  = f + 110592;         // 65536
  float* S      = f + 176128;         // 4194304 (16 MB)
  unsigned short* Prow = (unsigned short*)(f + 4370432);  // 8 MB
  unsigned short* PT   = Prow + 4194304;                  // 8 MB
  unsigned short* TT   = PT + 4194304;                    // 4 MB
  unsigned short* QT   = TT + 2097152;                    // 4 MB (total ~42.5 MB)

  rowdot_kernel<<<dim3((Bn * CL) / 4), 256, 0, stream>>>(C, w, nullptr, rc, Bn * CL);
  rowdot_kernel<<<dim3((Bn * QL) / 4), 256, 0, stream>>>(Q, w + Hh, bptr, cq, Bn * QL);
  prep_q_kernel<<<dim3(Hh / 64, Bn), 256, 0, stream>>>(Q, QT);
  s_mfma_kernel<<<dim3(CL / 64, Bn), 256, 0, stream>>>(C, Q, w + 2 * Hh, Qmask, rc, cq, S, Prow);
  colstat1_kernel<<<dim3(16, Bn), 256, 0, stream>>>(S, Cmask, partm, partl);
  colstat2_kernel<<<dim3(Bn), 128, 0, stream>>>(partm, partl, colm, colinv);
  pcol_kernel<<<dim3(CL / 64, Bn), 256, 0, stream>>>(S, Cmask, colm, colinv, PT);
  t_mfma_kernel<<<dim3(Hh / 32, Bn), 256, 0, stream>>>(C, PT, TT);
  out_mfma_kernel<<<dim3(Hh / 64, CL / 64, Bn), 256, 0, stream>>>(Prow, TT, QT, C, out);
}